// Round 8
// baseline (484.589 us; speedup 1.0000x reference)
//
#include <hip/hip_runtime.h>
#include <stdint.h>
#include <stddef.h>

typedef __attribute__((ext_vector_type(8))) _Float16 f16x8;
typedef __attribute__((ext_vector_type(4))) float f32x4;

#define D_IN 153
#define B_ROWS 262144
#define M_TILE 64
#define XB_STRIDE 168
#define G1H_STRIDE 68
#define H1_STRIDE 136
#define H2_STRIDE 72
#define HARENA 13312   // per-half arena bytes: max(xb 10752, g1h 4352+g2s 2048, h1 8704+h2 4608)

// swizzled f16 weight layout offsets (in u16 elements, all multiples of 512)
#define OFF_WP 0
#define SZ_WP (5*10*512)
#define OFF_WG1 (OFF_WP + SZ_WP)
#define SZ_WG1 (5*4*512)
#define OFF_WE1 (OFF_WG1 + SZ_WG1)
#define SZ_WE1 (8*5*8*512)
#define OFF_WE2 (OFF_WE1 + SZ_WE1)
#define SZ_WE2 (8*4*4*512)
#define OFF_WE3 (OFF_WE2 + SZ_WE2)
#define SZ_WE3 (8*2*512)
#define OFF_WG2 (OFF_WE3 + SZ_WE3)
#define SZ_WG2 (2*2*512)
#define OFF_WG3 (OFF_WG2 + SZ_WG2)
#define SZ_WG3 (1*512)
#define TOTAL_W (OFF_WG3 + SZ_WG3)   // 275968 u16 = 551936 B

__device__ __forceinline__ unsigned short f2h(float f) {
    _Float16 h = (_Float16)f;                 // v_cvt_f16_f32, RNE
    union { _Float16 h; unsigned short u; } v; v.h = h;
    return v.u;
}
__device__ __forceinline__ float h2f(unsigned short u) {
    union { unsigned short u; _Float16 h; } v; v.u = u;
    return (float)v.h;
}

__device__ __forceinline__ f32x4 mfma16(f16x8 a, f16x8 b, f32x4 c) {
    return __builtin_amdgcn_mfma_f32_16x16x32_f16(a, b, c, 0, 0, 0);
}

// A-fragment from LDS: A[m = lane&15][k = quad*8 + j], 16B contiguous per lane
__device__ __forceinline__ f16x8 ldsA(const unsigned short* buf, int stride,
                                      int m0, int k0, int lane) {
    int row = m0 + (lane & 15);
    int col = k0 + (lane >> 4) * 8;
    return *(const f16x8*)(buf + row * stride + col);
}
// B-fragment from pre-swizzled global: tile of 64 lanes x 16B
__device__ __forceinline__ f16x8 ldB(const unsigned short* ws, int tile, int lane) {
    return *(const f16x8*)(ws + (size_t)tile * 512 + lane * 8);
}

// ---------------------------------------------------------------------------
// Weight conversion: fp32 -> fp16 in MFMA B-fragment-swizzled layout.
// (unchanged from the verified version)
// ---------------------------------------------------------------------------
__global__ __launch_bounds__(256) void convert_weights(
        const float* __restrict__ Wp, const float* __restrict__ Wg1,
        const float* __restrict__ We1, const float* __restrict__ We2,
        const float* __restrict__ We3, const float* __restrict__ Wg2,
        const float* __restrict__ Wg3, unsigned short* __restrict__ ws) {
    int idx = blockIdx.x * 256 + threadIdx.x;
    if (idx >= TOTAL_W) return;
    int j = idx & 7;
    int lane = (idx >> 3) & 63;
    int t = idx >> 9;
    int quad = lane >> 4, nl = lane & 15;
    int kin = quad * 8 + j;
    float val = 0.f;
    if (idx < OFF_WG1) {                 // Wp [153][153], Kp=160 Np=160
        int kt = t / 10, nt = t % 10;
        int k = kt * 32 + kin, n = nt * 16 + nl;
        if (k < 153 && n < 153) val = Wp[k * 153 + n];
    } else if (idx < OFF_WE1) {          // Wg1 [153][64]
        int tt = t - (OFF_WG1 >> 9);
        int kt = tt / 4, nt = tt % 4;
        int k = kt * 32 + kin, n = nt * 16 + nl;
        if (k < 153) val = Wg1[k * 64 + n];
    } else if (idx < OFF_WE2) {          // We1 [8][153][128]
        int tt = t - (OFF_WE1 >> 9);
        int e = tt / 40, r = tt % 40, kt = r / 8, nt = r % 8;
        int k = kt * 32 + kin, n = nt * 16 + nl;
        if (k < 153) val = We1[((size_t)e * 153 + k) * 128 + n];
    } else if (idx < OFF_WE3) {          // We2 [8][128][64]
        int tt = t - (OFF_WE2 >> 9);
        int e = tt / 16, r = tt % 16, kt = r / 4, nt = r % 4;
        int k = kt * 32 + kin, n = nt * 16 + nl;
        val = We2[((size_t)e * 128 + k) * 64 + n];
    } else if (idx < OFF_WG2) {          // We3 [8][64][8], Np=16 (cols 8..15 zero)
        int tt = t - (OFF_WE3 >> 9);
        int e = tt / 2, kt = tt % 2;
        int k = kt * 32 + kin, n = nl;
        if (n < 8) val = We3[((size_t)e * 64 + k) * 8 + n];
    } else if (idx < OFF_WG3) {          // Wg2 [64][32]
        int tt = t - (OFF_WG2 >> 9);
        int kt = tt >> 1, nt = tt & 1;
        int k = kt * 32 + kin, n = nt * 16 + nl;
        val = Wg2[k * 32 + n];
    } else {                             // Wg3 [32][8] (cols 8..15 zero)
        int k = kin, n = nl;
        if (n < 8) val = Wg3[k * 8 + n];
    }
    ws[idx] = f2h(val);
}

// ---------------------------------------------------------------------------
// Fused MoE kernel, SOFTWARE-PIPELINED HALVES.
// The 64-row block is split into two independent 32-row halves H0/H1 run one
// phase apart: each inter-barrier segment executes {phase p of H0, phase p-1
// of H1} -- two INDEPENDENT dependency chains inside every wave's own
// instruction stream (R4 showed inter-wave overlap doesn't fill barrier-phase
// stalls; this fills them intra-wave). Per-half arenas (2 x 13312 B = same
// 26624 B), per-wave ldB count UNCHANGED (R5/R6: replication is the one hard
// no), total MFMA/VALU/LDS ops unchanged, 22 barriers (was 21). 2-wave
// phases pair complementarily: waves 0,1 own H0's Wg2/Wg3/We3/outLN; waves
// 2,3 own H1's. Per-row numerics byte-identical to the 258us R0 kernel.
// ---------------------------------------------------------------------------
__global__ __launch_bounds__(256, 2) void moe_main(
        const float* __restrict__ x,
        const float* __restrict__ ln_in_g, const float* __restrict__ ln_in_b,
        const float* __restrict__ bp,
        const float* __restrict__ bg1, const float* __restrict__ bg2,
        const float* __restrict__ bg3,
        const float* __restrict__ be1, const float* __restrict__ be2,
        const float* __restrict__ be3,
        const float* __restrict__ ln_out_g, const float* __restrict__ ln_out_b,
        const unsigned short* __restrict__ wsw,
        float* __restrict__ out) {
    const int tid = threadIdx.x;
    const int wave = tid >> 6, lane = tid & 63;
    const int quad = lane >> 4, nl = lane & 15;
    const int hw = wave >> 1;      // half owned for 2-wave phases
    const int sub = wave & 1;      // 16-row slice within that half
    const size_t rowBase = (size_t)blockIdx.x * M_TILE;

    __shared__ __align__(16) char U[2 * HARENA];                     // per-half arenas
    __shared__ __align__(16) unsigned short xp[M_TILE * XB_STRIDE];  // x_proj f16 (both halves)
    __shared__ __align__(16) float gate[M_TILE * 8];

    const f32x4 fzero = {0.f, 0.f, 0.f, 0.f};
    float oacc[4] = {0.f, 0.f, 0.f, 0.f};

    // arena(H): xb[32][168] -> g1h[32][68] + g2s(2x512 u16 @4352B) -> h1[32][136] + h2[32][72]@8704B
    auto arena = [&](int H) -> char* { return U + H * HARENA; };

    // ---- Phase LN(H): input LayerNorm, 32 rows, 8 threads/row ----
    auto ln_phase = [&](int H) {
        int r = tid >> 3, seg = tid & 7;
        unsigned short* xbh = (unsigned short*)arena(H);
        const float* xr = x + (rowBase + H * 32 + r) * (size_t)D_IN;
        float vals[20];
        float s = 0.f, sq = 0.f;
        #pragma unroll
        for (int i = 0; i < 20; i++) {
            int c = seg + i * 8;
            float v = (c < D_IN) ? xr[c] : 0.f;
            vals[i] = v; s += v; sq += v * v;
        }
        s += __shfl_xor(s, 1);  s += __shfl_xor(s, 2);  s += __shfl_xor(s, 4);
        sq += __shfl_xor(sq, 1); sq += __shfl_xor(sq, 2); sq += __shfl_xor(sq, 4);
        float mean = s * (1.f / 153.f);
        float var = sq * (1.f / 153.f) - mean * mean;
        float rstd = rsqrtf(var + 1e-5f);
        #pragma unroll
        for (int i = 0; i < 20; i++) {
            int c = seg + i * 8;
            if (c < D_IN) {
                float v = (vals[i] - mean) * rstd * ln_in_g[c] + ln_in_b[c];
                xbh[r * XB_STRIDE + c] = f2h(v);
            }
        }
        if (tid < 32) {
            #pragma unroll
            for (int c = D_IN; c < XB_STRIDE; c++) xbh[tid * XB_STRIDE + c] = 0;
        }
    };

    // ---- Phase Wp(H): x_proj = relu(x_norm @ Wp + bp) + x_norm (32 rows, N=160, K=160)
    auto wp_phase = [&](int H) {
        unsigned short* xbh = (unsigned short*)arena(H);
        f32x4 acc[3][2];
        #pragma unroll
        for (int q = 0; q < 3; q++)
            #pragma unroll
            for (int m = 0; m < 2; m++) acc[q][m] = fzero;
        const int nnt = (wave < 2) ? 3 : 2;
        #pragma unroll
        for (int kt = 0; kt < 5; kt++) {
            f16x8 a0 = ldsA(xbh, XB_STRIDE, 0,  kt * 32, lane);
            f16x8 a1 = ldsA(xbh, XB_STRIDE, 16, kt * 32, lane);
            #pragma unroll
            for (int q = 0; q < 3; q++) {
                if (q < nnt) {
                    int nt = wave + 4 * q;
                    f16x8 b = ldB(wsw, (OFF_WP >> 9) + kt * 10 + nt, lane);
                    acc[q][0] = mfma16(a0, b, acc[q][0]);
                    acc[q][1] = mfma16(a1, b, acc[q][1]);
                }
            }
        }
        #pragma unroll
        for (int q = 0; q < 3; q++) {
            if (q < nnt) {
                int nt = wave + 4 * q;
                int col = nt * 16 + nl;
                float bpv = (col < D_IN) ? bp[col] : 0.f;
                #pragma unroll
                for (int m = 0; m < 2; m++)
                    #pragma unroll
                    for (int i = 0; i < 4; i++) {
                        int row = m * 16 + quad * 4 + i;
                        float v = fmaxf(acc[q][m][i] + bpv, 0.f)
                                  + h2f(xbh[row * XB_STRIDE + col]);
                        xp[(H * 32 + row) * XB_STRIDE + col] = f2h(v);
                    }
            }
        }
        if (tid < 32) {
            #pragma unroll
            for (int c = 160; c < XB_STRIDE; c++) xp[(H * 32 + tid) * XB_STRIDE + c] = 0;
        }
    };

    // ---- Phase Wg1(H): g1 = relu(x_proj @ Wg1 + bg1) (32 rows, N=64, K=160)
    auto wg1_phase = [&](int H) {
        unsigned short* g1hh = (unsigned short*)arena(H);
        f32x4 acc0 = fzero, acc1 = fzero;
        #pragma unroll
        for (int kt = 0; kt < 5; kt++) {
            f16x8 a0 = ldsA(xp, XB_STRIDE, H * 32,      kt * 32, lane);
            f16x8 a1 = ldsA(xp, XB_STRIDE, H * 32 + 16, kt * 32, lane);
            f16x8 b = ldB(wsw, (OFF_WG1 >> 9) + kt * 4 + wave, lane);
            acc0 = mfma16(a0, b, acc0);
            acc1 = mfma16(a1, b, acc1);
        }
        int col = wave * 16 + nl;
        float bv = bg1[col];
        #pragma unroll
        for (int i = 0; i < 4; i++) {
            g1hh[(quad * 4 + i) * G1H_STRIDE + col]      = f2h(fmaxf(acc0[i] + bv, 0.f));
            g1hh[(16 + quad * 4 + i) * G1H_STRIDE + col] = f2h(fmaxf(acc1[i] + bv, 0.f));
        }
    };

    // ---- Phase Wg2(H): g2 = relu(g1 @ Wg2 + bg2), owning wave pair only ----
    auto wg2_phase = [&](int H) {
        if (hw != H) return;
        unsigned short* g1hh = (unsigned short*)arena(H);
        unsigned short* g2sh = (unsigned short*)(arena(H) + 4352);
        f16x8 a0 = ldsA(g1hh, G1H_STRIDE, sub * 16, 0,  lane);
        f16x8 a1 = ldsA(g1hh, G1H_STRIDE, sub * 16, 32, lane);
        f32x4 accg[2] = {fzero, fzero};
        #pragma unroll
        for (int nt = 0; nt < 2; nt++) {
            accg[nt] = mfma16(a0, ldB(wsw, (OFF_WG2 >> 9) + 0 * 2 + nt, lane), accg[nt]);
            accg[nt] = mfma16(a1, ldB(wsw, (OFF_WG2 >> 9) + 1 * 2 + nt, lane), accg[nt]);
        }
        unsigned short* g2w = g2sh + sub * 512;
        #pragma unroll
        for (int nt = 0; nt < 2; nt++) {
            float bv = bg2[nt * 16 + nl];
            #pragma unroll
            for (int i = 0; i < 4; i++) {
                int col = nt * 16 + nl;
                int row = quad * 4 + i;
                int off = (col >> 3) * 128 + row * 8 + (col & 7);
                g2w[off] = f2h(fmaxf(accg[nt][i] + bv, 0.f));
            }
        }
    };

    // ---- Phase Wg3(H): logits + softmax, owning wave pair only ----
    auto wg3_phase = [&](int H) {
        if (hw != H) return;
        unsigned short* g2sh = (unsigned short*)(arena(H) + 4352);
        f16x8 ag2 = *(const f16x8*)(g2sh + sub * 512 + lane * 8);
        f32x4 lg = mfma16(ag2, ldB(wsw, (OFF_WG3 >> 9), lane), fzero);
        float bg3v = (nl < 8) ? bg3[nl] : 0.f;
        #pragma unroll
        for (int i = 0; i < 4; i++) {
            float v = lg[i] + bg3v;
            float m = v;
            m = fmaxf(m, __shfl_xor(m, 1));
            m = fmaxf(m, __shfl_xor(m, 2));
            m = fmaxf(m, __shfl_xor(m, 4));
            float e = __expf(v - m);
            float ssum = e + __shfl_xor(e, 1);
            ssum += __shfl_xor(ssum, 2);
            ssum += __shfl_xor(ssum, 4);
            float g = e / ssum;
            if (nl < 8) {
                int row = H * 32 + sub * 16 + quad * 4 + i;
                gate[row * 8 + nl] = g;
                out[(size_t)B_ROWS * 8 + (rowBase + row) * 8 + nl] = g;
            }
        }
    };

    // ---- Phase We1(H,e): h1 = relu(x_proj @ We1[e] + be1[e]) (32 rows, N=128, K=160)
    auto we1_phase = [&](int H, int e) {
        unsigned short* h1h = (unsigned short*)arena(H);
        f32x4 acc[2][2];
        #pragma unroll
        for (int q = 0; q < 2; q++)
            #pragma unroll
            for (int m = 0; m < 2; m++) acc[q][m] = fzero;
        #pragma unroll
        for (int kt = 0; kt < 5; kt++) {
            f16x8 a0 = ldsA(xp, XB_STRIDE, H * 32,      kt * 32, lane);
            f16x8 a1 = ldsA(xp, XB_STRIDE, H * 32 + 16, kt * 32, lane);
            int tb = (OFF_WE1 >> 9) + (e * 5 + kt) * 8 + wave * 2;
            f16x8 b0 = ldB(wsw, tb, lane);
            f16x8 b1 = ldB(wsw, tb + 1, lane);
            acc[0][0] = mfma16(a0, b0, acc[0][0]);
            acc[0][1] = mfma16(a1, b0, acc[0][1]);
            acc[1][0] = mfma16(a0, b1, acc[1][0]);
            acc[1][1] = mfma16(a1, b1, acc[1][1]);
        }
        #pragma unroll
        for (int q = 0; q < 2; q++) {
            int col = wave * 32 + q * 16 + nl;
            float bv = be1[e * 128 + col];
            #pragma unroll
            for (int m = 0; m < 2; m++)
                #pragma unroll
                for (int i = 0; i < 4; i++) {
                    int row = m * 16 + quad * 4 + i;
                    h1h[row * H1_STRIDE + col] = f2h(fmaxf(acc[q][m][i] + bv, 0.f));
                }
        }
    };

    // ---- Phase We2(H,e): h2 = relu(h1 @ We2[e] + be2[e]) (32 rows, N=64, K=128)
    auto we2_phase = [&](int H, int e) {
        unsigned short* h1h = (unsigned short*)arena(H);
        unsigned short* h2h = (unsigned short*)(arena(H) + 8704);
        f32x4 acc0 = fzero, acc1 = fzero;
        #pragma unroll
        for (int kt = 0; kt < 4; kt++) {
            f16x8 a0 = ldsA(h1h, H1_STRIDE, 0,  kt * 32, lane);
            f16x8 a1 = ldsA(h1h, H1_STRIDE, 16, kt * 32, lane);
            f16x8 b = ldB(wsw, (OFF_WE2 >> 9) + (e * 4 + kt) * 4 + wave, lane);
            acc0 = mfma16(a0, b, acc0);
            acc1 = mfma16(a1, b, acc1);
        }
        int col = wave * 16 + nl;
        float bv = be2[e * 64 + col];
        #pragma unroll
        for (int i = 0; i < 4; i++) {
            h2h[(quad * 4 + i) * H2_STRIDE + col]      = f2h(fmaxf(acc0[i] + bv, 0.f));
            h2h[(16 + quad * 4 + i) * H2_STRIDE + col] = f2h(fmaxf(acc1[i] + bv, 0.f));
        }
    };

    // ---- Phase We3(H,e): gated accumulate, owning wave pair only ----
    auto we3_phase = [&](int H, int e) {
        if (hw != H) return;
        unsigned short* h2h = (unsigned short*)(arena(H) + 8704);
        f32x4 acc = fzero;
        #pragma unroll
        for (int kt = 0; kt < 2; kt++) {
            f16x8 a = ldsA(h2h, H2_STRIDE, sub * 16, kt * 32, lane);
            f16x8 b = ldB(wsw, (OFF_WE3 >> 9) + e * 2 + kt, lane);
            acc = mfma16(a, b, acc);
        }
        if (nl < 8) {
            float bv = be3[e * 8 + nl];
            #pragma unroll
            for (int i = 0; i < 4; i++) {
                int row = H * 32 + sub * 16 + quad * 4 + i;
                oacc[i] += gate[row * 8 + e] * (acc[i] + bv);
            }
        }
    };

    // ---- Phase LNout(H): output LayerNorm over 8 + store, owning wave pair ----
    auto lnout_phase = [&](int H) {
        if (hw != H) return;
        float go = 1.f, bo = 0.f;
        if (nl < 8) { go = ln_out_g[nl]; bo = ln_out_b[nl]; }
        #pragma unroll
        for (int i = 0; i < 4; i++) {
            float v = oacc[i];
            float s = v + __shfl_xor(v, 1);
            s += __shfl_xor(s, 2);
            s += __shfl_xor(s, 4);
            float q2 = v * v;
            float q = q2 + __shfl_xor(q2, 1);
            q += __shfl_xor(q, 2);
            q += __shfl_xor(q, 4);
            float mean = s * 0.125f;
            float var = q * 0.125f - mean * mean;
            float rstd = rsqrtf(var + 1e-5f);
            float ov = (v - mean) * rstd * go + bo;
            if (nl < 8) {
                size_t row = rowBase + H * 32 + sub * 16 + quad * 4 + i;
                out[row * 8 + nl] = ov;
            }
        }
    };

    // ---- Pipelined schedule: segment s = {phase p(H0), phase p-1(H1)} ----
    ln_phase(0);                         __syncthreads();   // s1
    wp_phase(0);   ln_phase(1);          __syncthreads();   // s2
    wg1_phase(0);  wp_phase(1);          __syncthreads();   // s3
    wg2_phase(0);  wg1_phase(1);         __syncthreads();   // s4
    wg3_phase(0);  wg2_phase(1);         __syncthreads();   // s5
    we1_phase(0, 0); wg3_phase(1);       __syncthreads();   // s6
    we2_phase(0, 0); we1_phase(1, 0);    __syncthreads();   // s7
    for (int e = 1; e < 8; e++) {
        // seg A: We3[e-1](H0) + We1[e](H0) + We2[e-1](H1)
        we3_phase(0, e - 1); we1_phase(0, e); we2_phase(1, e - 1);
        __syncthreads();
        // seg B: We2[e](H0) + We3[e-1](H1) + We1[e](H1)
        we2_phase(0, e); we3_phase(1, e - 1); we1_phase(1, e);
        __syncthreads();
    }
    // tail
    we3_phase(0, 7); lnout_phase(0); we2_phase(1, 7);
    __syncthreads();                                        // s22
    we3_phase(1, 7); lnout_phase(1);
}

extern "C" void kernel_launch(void* const* d_in, const int* in_sizes, int n_in,
                              void* d_out, int out_size, void* d_ws, size_t ws_size,
                              hipStream_t stream) {
    const float* x        = (const float*)d_in[0];
    const float* ln_in_g  = (const float*)d_in[1];
    const float* ln_in_b  = (const float*)d_in[2];
    const float* Wp       = (const float*)d_in[3];
    const float* bp       = (const float*)d_in[4];
    const float* Wg1      = (const float*)d_in[5];
    const float* bg1      = (const float*)d_in[6];
    const float* Wg2      = (const float*)d_in[7];
    const float* bg2      = (const float*)d_in[8];
    const float* Wg3      = (const float*)d_in[9];
    const float* bg3      = (const float*)d_in[10];
    const float* We1      = (const float*)d_in[11];
    const float* be1      = (const float*)d_in[12];
    const float* We2      = (const float*)d_in[13];
    const float* be2      = (const float*)d_in[14];
    const float* We3      = (const float*)d_in[15];
    const float* be3      = (const float*)d_in[16];
    const float* ln_out_g = (const float*)d_in[17];
    const float* ln_out_b = (const float*)d_in[18];
    unsigned short* ws = (unsigned short*)d_ws;
    float* out = (float*)d_out;

    convert_weights<<<(TOTAL_W + 255) / 256, 256, 0, stream>>>(
        Wp, Wg1, We1, We2, We3, Wg2, Wg3, ws);
    moe_main<<<B_ROWS / M_TILE, 256, 0, stream>>>(
        x, ln_in_g, ln_in_b, bp, bg1, bg2, bg3,
        be1, be2, be3, ln_out_g, ln_out_b, ws, out);
}